// Round 1
// 1017.123 us; speedup vs baseline: 1.0450x; 1.0450x over previous
//
#include <hip/hip_runtime.h>
#include <math.h>

// RecurrentSlotEncoder: B=16,K=16,N=1024,D=256,L=8
// Algebra: scores = (slots@Wqk) @ h^T      (no K-projection of h)
//          gi     = (attn@h)·rden @ WgiT + bgi, Wgi = W_ih@Wv  (no V-projection)
// R4 structure: per step = attn (512 wgs, 32-row tiles)
//   + gru_kernel (256 wgs = (b,kc16)): K-split GRU partials, weight slice (16x768
//     per matrix) staged in LDS once and reused by all 8 slot rows of the batch
//     -> GRU weight traffic 192MB/step -> 24.6MB/step, on all 256 CUs.
//   + chain2_kernel (128 wgs = (b,l)): combine partials -> GRU nonlin -> FFN ->
//     LN -> next Qk (phases identical to R3 chain phases 2-4).

#define Bn 16
#define KK 16
#define Nn 1024
#define Dn 256
#define Ln 8

// workspace float offsets
#define OFF_WQK   0          // 256*256   Wqk[d][e]
#define OFF_BQK   65536      // 256
#define OFF_WGIT  65792      // 256*768   WgiT[e][jj] = sum_c Wih[jj][c]*Wv[c][e]
#define OFF_BGI   262400     // 768
#define OFF_WHHT  263168     // 256*768   WhhT[e][jj] = Whh[jj][e]
#define OFF_W1T   459776     // 256*256
#define OFF_W2T   525312     // 256*256
#define OFF_SLOTS 590848     // 128*256
#define OFF_QK    623616     // 128*256
#define OFF_PAV   656384     // 16*32*8*256 = 1048576
#define OFF_PDEN  1704960    // 16*32*8 = 4096
#define OFF_PG    1709056    // 16*16*8*1536 = 3145728 (GRU partials)

__device__ __forceinline__ float sigmoidf_(float x) { return 1.f / (1.f + __expf(-x)); }

// P1: Wqk[d][e] = sum_a Wq[a][d]*Wk[a][e]; bqk[e] = sum_a bq[a]*Wk[a][e]
__global__ __launch_bounds__(256) void p1_kernel(
    const float* __restrict__ Wq, const float* __restrict__ bq,
    const float* __restrict__ Wk, float* __restrict__ Wqk, float* __restrict__ bqk) {
  int w = blockIdx.x, tid = threadIdx.x;
  if (w < 256) {
    float acc = 0.f;
    for (int a = 0; a < 256; ++a) acc += Wq[a * 256 + w] * Wk[a * 256 + tid];
    Wqk[w * 256 + tid] = acc;
  } else {
    float acc = 0.f;
    for (int a = 0; a < 256; ++a) acc += bq[a] * Wk[a * 256 + tid];
    bqk[tid] = acc;
  }
}

// P2: WgiT[e*768+jj] = sum_c Wih[jj][c]*Wv[c][e]; bgi[jj]=bih[jj]+sum_c Wih[jj][c]*bv[c]
__global__ __launch_bounds__(256) void p2_kernel(
    const float* __restrict__ Wih, const float* __restrict__ bih,
    const float* __restrict__ Wv, const float* __restrict__ bv,
    float* __restrict__ WgiT, float* __restrict__ bgi) {
  int d = blockIdx.x, tid = threadIdx.x;
  float a0 = 0.f, a1 = 0.f, a2 = 0.f;
  for (int c = 0; c < 256; ++c) {
    float wv = Wv[c * 256 + d];  // wave-uniform
    a0 += Wih[tid * 256 + c] * wv;
    a1 += Wih[(tid + 256) * 256 + c] * wv;
    a2 += Wih[(tid + 512) * 256 + c] * wv;
  }
  WgiT[d * 768 + tid] = a0;
  WgiT[d * 768 + 256 + tid] = a1;
  WgiT[d * 768 + 512 + tid] = a2;
  if (d < 3) {
    int jj = d * 256 + tid;
    float s = bih[jj];
    for (int c = 0; c < 256; ++c) s += Wih[jj * 256 + c] * bv[c];
    bgi[jj] = s;
  }
}

// P3: LDS tile transposes: WhhT (768x256 -> 256x768), W1T, W2T (256x256)
__global__ __launch_bounds__(256) void p3_kernel(
    const float* __restrict__ Whh, const float* __restrict__ W1,
    const float* __restrict__ W2, float* __restrict__ WhhT,
    float* __restrict__ W1T, float* __restrict__ W2T) {
  __shared__ float tile[32][33];
  int wg = blockIdx.x, tid = threadIdx.x;
  const float* in; float* out; int R, C, tr, tc;
  if (wg < 192)      { in = Whh; out = WhhT; R = 768; C = 256; wg -= 0;   tr = wg >> 3; tc = wg & 7; }
  else if (wg < 256) { in = W1;  out = W1T;  R = 256; C = 256; wg -= 192; tr = wg >> 3; tc = wg & 7; }
  else               { in = W2;  out = W2T;  R = 256; C = 256; wg -= 256; tr = wg >> 3; tc = wg & 7; }
  int r = tid >> 5, c = tid & 31;
#pragma unroll
  for (int k = 0; k < 4; ++k)
    tile[r + 8 * k][c] = in[(tr * 32 + r + 8 * k) * C + tc * 32 + c];
  __syncthreads();
#pragma unroll
  for (int k = 0; k < 4; ++k)
    out[(tc * 32 + r + 8 * k) * R + tr * 32 + c] = tile[c][r + 8 * k];
}

__global__ __launch_bounds__(256) void init_slots_kernel(
    const float* __restrict__ eps, const float* __restrict__ mu,
    const float* __restrict__ lsig, float* __restrict__ slots) {
  int idx = blockIdx.x * 256 + threadIdx.x;  // 32768
  int r = idx & 2047;
  slots[idx] = mu[r] + expf(lsig[r]) * eps[idx];
}

// Qk = slots @ Wqk + bqk (t=0 only)
__global__ __launch_bounds__(256) void qk0_kernel(
    const float* __restrict__ Wqk, const float* __restrict__ bqk,
    const float* __restrict__ slots, float* __restrict__ Qkout) {
  __shared__ float sl_s[2048];
  int j = blockIdx.x & 7, b = blockIdx.x >> 3, tid = threadIdx.x;
  for (int k = 0; k < 8; ++k) sl_s[tid + k * 256] = slots[b * 2048 + tid + k * 256];
  __syncthreads();
  int l = tid >> 5, ee = j * 32 + (tid & 31);
  float acc = bqk[ee];
  for (int d = 0; d < 256; ++d) acc += sl_s[l * 256 + d] * Wqk[d * 256 + ee];
  Qkout[b * 2048 + l * 256 + ee] = acc;
}

// Fused attention: wg = (tile32, b), grid (32,16). Stages 32 rows of H in LDS,
// computes exp-scores (unnormalized Beta), per-tile denom, per-tile attn@H.
__global__ __launch_bounds__(256) void attn_kernel(
    const float* __restrict__ H, const float* __restrict__ Qk,
    float* __restrict__ beta_out, float* __restrict__ par_av,
    float* __restrict__ par_den, int t) {
  __shared__ float h_s[32 * 258];
  __shared__ float qk_s[Ln * Dn];
  __shared__ float e_s[256];
  __shared__ float red[256];
  int tile = blockIdx.x, b = blockIdx.y, tid = threadIdx.x;
#pragma unroll
  for (int k = 0; k < 8; ++k) qk_s[tid + k * 256] = Qk[b * 2048 + tid + k * 256];
  const float* Hbase = H + (((long)b * KK + t) * Nn + tile * 32) * Dn;
  const float4* src = (const float4*)Hbase;
#pragma unroll
  for (int k = 0; k < 8; ++k) {
    int idx4 = tid + k * 256;  // 0..2047 coalesced
    int r = idx4 >> 6, d4 = idx4 & 63;
    float4 v = src[idx4];
    float* dst = &h_s[r * 258 + d4 * 4];
    ((float2*)dst)[0] = make_float2(v.x, v.y);
    ((float2*)dst)[1] = make_float2(v.z, v.w);
  }
  __syncthreads();
  int l = tid >> 5, row = tid & 31;
  // phase A: scores
  {
    const float2* hr2 = (const float2*)(&h_s[row * 258]);
    const float2* qr2 = (const float2*)(&qk_s[l * 256]);
    float acc = 0.f;
#pragma unroll 8
    for (int e = 0; e < 128; ++e) {
      float2 hv = hr2[e], qv = qr2[e];
      acc += hv.x * qv.x + hv.y * qv.y;
    }
    float ev = __expf(acc * 0.0625f);  // 1/sqrt(256); no max-sub (|s| small)
    e_s[tid] = ev;
    red[tid] = ev;
    beta_out[(((long)b * KK + t) * Ln + l) * Nn + tile * 32 + row] = ev;
  }
  __syncthreads();
  if (tid < 8) {
    float s = 0.f;
    for (int i = 0; i < 32; ++i) s += red[tid * 32 + i];
    par_den[(b * 32 + tile) * 8 + tid] = s;
  }
  // phase B: av[l] += e[l,row] * h[row, d=tid]
  float av[8];
#pragma unroll
  for (int i = 0; i < 8; ++i) av[i] = 0.f;
  for (int rr = 0; rr < 32; ++rr) {
    float hv = h_s[rr * 258 + tid];
#pragma unroll
    for (int i = 0; i < 8; ++i) av[i] += e_s[i * 32 + rr] * hv;
  }
  long pbase = (long)(b * 32 + tile) * 2048;
#pragma unroll
  for (int i = 0; i < 8; ++i) par_av[pbase + i * 256 + tid] = av[i];
}

// GRU partial kernel: wg = (b, kc16), grid 256 x 1024 threads.
// Each wg owns a 16-row K-slice of WgiT/WhhT (staged in LDS, 48KB at a time)
// and computes partial gi/gh for ALL 8 slot rows of batch b.
// Also: reduces par_av -> upd (scaled by 1/den), normalizes its Beta slice.
// pg layout: [((b*16+kc)*8+l)*1536 + col]; gi at col c+{0,256,512}, gh at 768+...
__global__ __launch_bounds__(1024) void gru_kernel(
    const float* __restrict__ WgiT, const float* __restrict__ WhhT,
    const float* __restrict__ par_av, const float* __restrict__ par_den,
    const float* __restrict__ slots, float* __restrict__ Beta,
    float* __restrict__ pg, int t) {
  __shared__ float w_s[16 * 768];  // 48KB staged weight slice (reused gi -> gh)
  __shared__ float rupd[8][128];
  __shared__ float upd_s[128];     // [l*16+e], scaled by 1/den
  __shared__ float sl_s[128];      // slots slice [l*16+e]
  __shared__ float den_s[8];
  int b = blockIdx.x >> 4, kc = blockIdx.x & 15;
  int tid = threadIdx.x;

  // region 1: stage WgiT slice; par_av partial reduce; den; slots slice
  const float4* wsrc = (const float4*)(WgiT + kc * 12288);
  float4 wv0 = wsrc[tid], wv1 = wsrc[tid + 1024], wv2 = wsrc[tid + 2048];
  {
    int g = tid >> 7, le = tid & 127;       // le = l*16+e
    int l = le >> 4, e = le & 15;
    float ps = 0.f;
    long base = ((long)(b * 32)) * 2048 + l * 256 + kc * 16 + e;
#pragma unroll
    for (int i = 0; i < 4; ++i) ps += par_av[base + (long)(g * 4 + i) * 2048];
    rupd[g][le] = ps;
  }
  if (tid < 256) {
    int ll = tid >> 5, tl = tid & 31;
    float dv = par_den[(b * 32 + tl) * 8 + ll];
#pragma unroll
    for (int m = 1; m < 32; m <<= 1) dv += __shfl_xor(dv, m);
    if (tl == 0) den_s[ll] = 1.f / dv;
  }
  if (tid < 128) sl_s[tid] = slots[b * 2048 + (tid >> 4) * 256 + kc * 16 + (tid & 15)];
  ((float4*)w_s)[tid] = wv0;
  ((float4*)w_s)[tid + 1024] = wv1;
  ((float4*)w_s)[tid + 2048] = wv2;
  __syncthreads();

  // region 2: Beta normalize (slice of 512) + finalize scaled upd
  if (tid < 512) {
    int idx = kc * 512 + tid;  // = l*1024 + n
    Beta[(((long)b * KK + t) * Ln) * Nn + idx] *= den_s[idx >> 10];
  }
  if (tid < 128) {
    float s = 0.f;
#pragma unroll
    for (int g = 0; g < 8; ++g) s += rupd[g][tid];
    upd_s[tid] = s * den_s[tid >> 4];
  }
  __syncthreads();

  // region 3: gi partials. thread = (l4 = tid>>8, cb = tid&255) covers rows
  // {l4, l4+4} and cols {cb, cb+256, cb+512}: each LDS weight read serves 2 rows.
  int l4 = tid >> 8, cb = tid & 255;
  long pb0 = ((long)(b * 16 + kc) * 8 + l4) * 1536;
  long pb1 = ((long)(b * 16 + kc) * 8 + l4 + 4) * 1536;
  {
    float a0 = 0.f, a1 = 0.f, a2 = 0.f, a3 = 0.f, a4 = 0.f, a5 = 0.f;
#pragma unroll
    for (int e = 0; e < 16; ++e) {
      float u0 = upd_s[l4 * 16 + e];
      float u1 = upd_s[(l4 + 4) * 16 + e];
      float w0 = w_s[e * 768 + cb];
      float w1 = w_s[e * 768 + 256 + cb];
      float w2 = w_s[e * 768 + 512 + cb];
      a0 += u0 * w0; a1 += u0 * w1; a2 += u0 * w2;
      a3 += u1 * w0; a4 += u1 * w1; a5 += u1 * w2;
    }
    pg[pb0 + cb] = a0; pg[pb0 + 256 + cb] = a1; pg[pb0 + 512 + cb] = a2;
    pg[pb1 + cb] = a3; pg[pb1 + 256 + cb] = a4; pg[pb1 + 512 + cb] = a5;
  }
  __syncthreads();
  // region 4: stage WhhT slice into same LDS
  {
    const float4* hsrc = (const float4*)(WhhT + kc * 12288);
    ((float4*)w_s)[tid] = hsrc[tid];
    ((float4*)w_s)[tid + 1024] = hsrc[tid + 1024];
    ((float4*)w_s)[tid + 2048] = hsrc[tid + 2048];
  }
  __syncthreads();
  // region 5: gh partials (cols 768..1535)
  {
    float a0 = 0.f, a1 = 0.f, a2 = 0.f, a3 = 0.f, a4 = 0.f, a5 = 0.f;
#pragma unroll
    for (int e = 0; e < 16; ++e) {
      float s0 = sl_s[l4 * 16 + e];
      float s1 = sl_s[(l4 + 4) * 16 + e];
      float w0 = w_s[e * 768 + cb];
      float w1 = w_s[e * 768 + 256 + cb];
      float w2 = w_s[e * 768 + 512 + cb];
      a0 += s0 * w0; a1 += s0 * w1; a2 += s0 * w2;
      a3 += s1 * w0; a4 += s1 * w1; a5 += s1 * w2;
    }
    pg[pb0 + 768 + cb] = a0; pg[pb0 + 1024 + cb] = a1; pg[pb0 + 1280 + cb] = a2;
    pg[pb1 + 768 + cb] = a3; pg[pb1 + 1024 + cb] = a4; pg[pb1 + 1280 + cb] = a5;
  }
}

// Combine + rest of chain: wg = (b,l), 128 wgs x 1024 threads (q = tid>>8 splits
// K=256 into 4 chunks; c = tid&255 output column). Phases:
// combine GRU partials -> nonlin/s2 -> f1 -> ffn+LN -> next Qk.
__global__ __launch_bounds__(1024) void chain2_kernel(
    const float* __restrict__ pg, const float* __restrict__ bgi,
    const float* __restrict__ bhh,
    const float* __restrict__ W1T, const float* __restrict__ b1,
    const float* __restrict__ W2T, const float* __restrict__ b2,
    const float* __restrict__ Wqk, const float* __restrict__ bqk,
    const float* __restrict__ ln_g, const float* __restrict__ ln_b,
    float* __restrict__ slots, float* __restrict__ S, float* __restrict__ Qk,
    int t) {
  __shared__ float sl_s[256], s2_s[256], f_s[256], s3_s[256];
  __shared__ float red6[6][4][256];
  __shared__ float lnred[8];
  int b = blockIdx.x >> 3, l = blockIdx.x & 7;
  int tid = threadIdx.x, q = tid >> 8, c = tid & 255;

  if (tid < 256) sl_s[tid] = slots[b * 2048 + l * 256 + tid];
  // phase 0: combine GRU partials over kc = q*4 .. q*4+3
  {
    float ir = 0, iz = 0, in_ = 0, hr = 0, hz = 0, hn = 0;
#pragma unroll
    for (int j = 0; j < 4; ++j) {
      const float* p = pg + ((long)(b * 16 + q * 4 + j) * 8 + l) * 1536;
      ir += p[c];        iz += p[256 + c];   in_ += p[512 + c];
      hr += p[768 + c];  hz += p[1024 + c];  hn  += p[1280 + c];
    }
    red6[0][q][c] = ir; red6[1][q][c] = iz; red6[2][q][c] = in_;
    red6[3][q][c] = hr; red6[4][q][c] = hz; red6[5][q][c] = hn;
  }
  __syncthreads();
  if (q == 0) {
    float tir = red6[0][0][c] + red6[0][1][c] + red6[0][2][c] + red6[0][3][c] + bgi[c];
    float tiz = red6[1][0][c] + red6[1][1][c] + red6[1][2][c] + red6[1][3][c] + bgi[256 + c];
    float tin = red6[2][0][c] + red6[2][1][c] + red6[2][2][c] + red6[2][3][c] + bgi[512 + c];
    float thr = red6[3][0][c] + red6[3][1][c] + red6[3][2][c] + red6[3][3][c] + bhh[c];
    float thz = red6[4][0][c] + red6[4][1][c] + red6[4][2][c] + red6[4][3][c] + bhh[256 + c];
    float thn = red6[5][0][c] + red6[5][1][c] + red6[5][2][c] + red6[5][3][c] + bhh[512 + c];
    float r = sigmoidf_(tir + thr);
    float z = sigmoidf_(tiz + thz);
    float n = tanhf(tin + r * thn);
    s2_s[c] = (1.f - z) * n + z * sl_s[c];
  }
  __syncthreads();

  // phase 2: f1 = relu(s2 @ W1^T + b1)
  {
    float f = 0.f;
#pragma unroll 4
    for (int i = 0; i < 64; ++i) {
      int e = q * 64 + i;
      f += s2_s[e] * W1T[e * 256 + c];
    }
    red6[0][q][c] = f;
  }
  __syncthreads();
  if (q == 0)
    f_s[c] = fmaxf(red6[0][0][c] + red6[0][1][c] + red6[0][2][c] + red6[0][3][c] + b1[c], 0.f);
  __syncthreads();

  // phase 3: x = s2 + f1 @ W2^T + b2, then LayerNorm
  {
    float x = 0.f;
#pragma unroll 4
    for (int i = 0; i < 64; ++i) {
      int e = q * 64 + i;
      x += f_s[e] * W2T[e * 256 + c];
    }
    red6[1][q][c] = x;
  }
  __syncthreads();
  float xv = 0.f;
  if (q == 0) {
    xv = red6[1][0][c] + red6[1][1][c] + red6[1][2][c] + red6[1][3][c] + b2[c] + s2_s[c];
    float sr = xv, qr = xv * xv;
#pragma unroll
    for (int m = 1; m < 64; m <<= 1) {
      sr += __shfl_xor(sr, m);
      qr += __shfl_xor(qr, m);
    }
    if ((c & 63) == 0) { lnred[c >> 6] = sr; lnred[4 + (c >> 6)] = qr; }
  }
  __syncthreads();
  if (q == 0) {
    float m = (lnred[0] + lnred[1] + lnred[2] + lnred[3]) * (1.f / 256.f);
    float v = (lnred[4] + lnred[5] + lnred[6] + lnred[7]) * (1.f / 256.f) - m * m;
    float s3 = (xv - m) * rsqrtf(v + 1e-5f) * ln_g[c] + ln_b[c];
    s3_s[c] = s3;
    S[(((long)b * KK + t) * Ln + l) * Dn + c] = s3;
    slots[b * 2048 + l * 256 + c] = s3;
  }
  __syncthreads();

  // phase 4: next Qk = s3 @ Wqk + bqk
  {
    float qacc = 0.f;
#pragma unroll 4
    for (int i = 0; i < 64; ++i) {
      int e = q * 64 + i;
      qacc += s3_s[e] * Wqk[e * 256 + c];
    }
    red6[0][q][c] = qacc;
  }
  __syncthreads();
  if (q == 0)
    Qk[b * 2048 + l * 256 + c] =
        red6[0][0][c] + red6[0][1][c] + red6[0][2][c] + red6[0][3][c] + bqk[c];
}

extern "C" void kernel_launch(void* const* d_in, const int* in_sizes, int n_in,
                              void* d_out, int out_size, void* d_ws, size_t ws_size,
                              hipStream_t stream) {
  const float* H    = (const float*)d_in[0];
  const float* eps  = (const float*)d_in[1];
  const float* mu   = (const float*)d_in[2];
  const float* lsig = (const float*)d_in[3];
  const float* Wq   = (const float*)d_in[4];
  const float* bq   = (const float*)d_in[5];
  const float* Wk   = (const float*)d_in[6];
  // d_in[7] = bk: constant per softmax row -> drops out
  const float* Wv   = (const float*)d_in[8];
  const float* bv   = (const float*)d_in[9];
  const float* Wih  = (const float*)d_in[10];
  const float* bih  = (const float*)d_in[11];
  const float* Whh  = (const float*)d_in[12];
  const float* bhh  = (const float*)d_in[13];
  const float* W1   = (const float*)d_in[14];
  const float* b1   = (const float*)d_in[15];
  const float* W2   = (const float*)d_in[16];
  const float* b2   = (const float*)d_in[17];
  const float* ln_g = (const float*)d_in[18];
  const float* ln_b = (const float*)d_in[19];

  float* out = (float*)d_out;
  float* S    = out;                            // [B,K,L,D]
  float* Beta = out + (long)Bn * KK * Ln * Dn;  // [B,K,L,N]

  float* ws = (float*)d_ws;
  float* Wqk   = ws + OFF_WQK;
  float* bqk   = ws + OFF_BQK;
  float* WgiT  = ws + OFF_WGIT;
  float* bgi   = ws + OFF_BGI;
  float* WhhT  = ws + OFF_WHHT;
  float* W1T   = ws + OFF_W1T;
  float* W2T   = ws + OFF_W2T;
  float* slots = ws + OFF_SLOTS;
  float* Qk    = ws + OFF_QK;
  float* pav   = ws + OFF_PAV;
  float* pden  = ws + OFF_PDEN;
  float* pg    = ws + OFF_PG;

  p1_kernel<<<257, 256, 0, stream>>>(Wq, bq, Wk, Wqk, bqk);
  p2_kernel<<<256, 256, 0, stream>>>(Wih, bih, Wv, bv, WgiT, bgi);
  p3_kernel<<<320, 256, 0, stream>>>(Whh, W1, W2, WhhT, W1T, W2T);
  init_slots_kernel<<<128, 256, 0, stream>>>(eps, mu, lsig, slots);
  qk0_kernel<<<128, 256, 0, stream>>>(Wqk, bqk, slots, Qk);

  for (int t = 0; t < KK; ++t) {
    attn_kernel<<<dim3(32, 16), 256, 0, stream>>>(H, Qk, Beta, pav, pden, t);
    gru_kernel<<<256, 1024, 0, stream>>>(WgiT, WhhT, pav, pden, slots, Beta, pg, t);
    chain2_kernel<<<128, 1024, 0, stream>>>(pg, bgi, bhh, W1T, b1, W2T, b2,
                                            Wqk, bqk, ln_g, ln_b, slots, S, Qk, t);
  }
}